// Round 10
// baseline (267.371 us; speedup 1.0000x reference)
//
#include <hip/hip_runtime.h>
#include <hip/hip_bf16.h>
#include <stdint.h>

// EdgeDecoder: out = relu(concat(zd[row], zt[col]) @ W1 + b1) @ W2 + b2
// R12 = R11 (algorithmic split: U = zd@W1d, V = zt@W1t dense GEMMs, then a
// pure streaming gather pass) + occupancy fix on the gather pass:
//   - edge_kernel __launch_bounds__(256,8): R11's (256,4) capped it at 4
//     blocks/CU (Occupancy 47%); gathers are latency-bound -> double waves.
//   - b1 folded into U at uv_gemm store: frees the b1v[32] array in the hot
//     kernel (register headroom under the 64-VGPR/8-wave cap).
// Everything else byte-identical to R11.

typedef unsigned short u16;
typedef __attribute__((ext_vector_type(8))) short short8;
typedef __attribute__((ext_vector_type(4))) float f32x4;

#define HDIM 256
#define KDIM 512
#define BK 64

__device__ __forceinline__ u16 f2bf(float f) {
  union { float f; uint32_t u; } v; v.f = f;
  uint32_t u = v.u;
  return (u16)((u + 0x7fffu + ((u >> 16) & 1u)) >> 16);   // RNE, inputs finite
}
__device__ __forceinline__ u16 f2h(float f) {
  union { _Float16 h; u16 u; } v; v.h = (_Float16)f;      // v_cvt_f16_f32 RNE
  return v.u;
}
__device__ __forceinline__ float h2f(u16 b) {
  union { _Float16 h; u16 u; } v; v.u = b;
  return (float)v.h;
}

// async global->LDS, 16B per lane; LDS dest must be wave-uniform base (+lane*16)
__device__ __forceinline__ void gl2lds16(const void* g, void* l) {
  __builtin_amdgcn_global_load_lds(
      (const __attribute__((address_space(1))) unsigned int*)g,
      (__attribute__((address_space(3))) unsigned int*)l,
      16, 0, 0);
}

// Prep: 64x64 LDS-tiled transpose of W1 (512x256 fp32 -> W1T 256x512 bf16),
// coalesced both sides. 32 blocks, ~3us.
__global__ void prep_w1t(const float* __restrict__ w1, u16* __restrict__ w1t) {
  const int b = blockIdx.x;
  __shared__ float tile[64][65];
  const int k0 = (b >> 2) * 64, n0 = (b & 3) * 64;
  const int tx = threadIdx.x & 63, ty = threadIdx.x >> 6;
#pragma unroll
  for (int i = ty; i < 64; i += 4)
    tile[i][tx] = w1[(size_t)(k0 + i) * HDIM + n0 + tx];
  __syncthreads();
#pragma unroll
  for (int i = ty; i < 64; i += 4)
    w1t[(size_t)(n0 + i) * KDIM + k0 + tx] = f2bf(tile[tx][i]);
}

// UV GEMM: blocks [0,nUb) compute U = zd @ W1d (+b1 folded), blocks [nUb,..)
// V = zt @ W1t. Block = 128 rows x 128 cols, 4 waves, wave = 32 rows x 128
// cols, acc[2][8]. Sequential rows: A from fp32 z (coalesced) cvt in-reg.
// K = 256 -> 4 chunks of BK=64; W1T k-chunk base kb = 0 (U) or 4 (V).
__global__ __launch_bounds__(256, 2) void uv_gemm(
    const float* __restrict__ zdf, const float* __restrict__ ztf,
    const u16* __restrict__ w1t, const float* __restrict__ b1,
    u16* __restrict__ Uh, u16* __restrict__ Vh,
    int ND, int NT, int nUb) {
  __shared__ u16 lB[2][128 * BK];   // 2 x 16KB [n_local][k], XOR-swizzled

  const int bid = blockIdx.x;
  const int isV = (bid >= nUb);
  const int lb  = isV ? (bid - nUb) : bid;
  const float* zf = isV ? ztf : zdf;
  u16* Oh = isV ? Vh : Uh;
  const int NR = isV ? NT : ND;
  const int r0 = (lb >> 1) * 128;
  const int n0 = (lb & 1) * 128;
  const int kb = isV ? 4 : 0;       // k-chunk base into W1T's 512-k dim

  const int tid   = threadIdx.x;
  const int wid   = tid >> 6;
  const int lane  = tid & 63;
  const int r8    = lane >> 3;
  const int slog  = ((lane & 7) ^ (r8 & 7)) * 8;   // inv-swizzled src piece
  const int colid = lane & 15;
  const int quad  = lane >> 4;
  const int csw   = colid & 7;

  const u16* pB = w1t + (uint32_t)(n0 + wid * 32 + r8) * KDIM + slog;
  u16* lBw0 = &lB[0][(wid * 32) * BK];
  u16* lBw1 = &lB[1][(wid * 32) * BK];

  uint32_t offR[2];
#pragma unroll
  for (int rt = 0; rt < 2; ++rt) {
    int r = min(r0 + wid * 32 + rt * 16 + colid, NR - 1);
    offR[rt] = (uint32_t)r * HDIM;
  }

  f32x4 acc[2][8];
#pragma unroll
  for (int i = 0; i < 2; ++i)
#pragma unroll
    for (int j = 0; j < 8; ++j) acc[i][j] = f32x4{0.f, 0.f, 0.f, 0.f};

  float4 a32[2][2][2][2];  // [buf][rt][s][half] in-flight fp32 A
  short8 aB[2][2][2];      // [buf][rt][s] bf16 fragments

  auto loadA = [&](int kc, int buf) {
#pragma unroll
    for (int rt = 0; rt < 2; ++rt)
#pragma unroll
      for (int s = 0; s < 2; ++s) {
        const float* p = zf + offR[rt] + kc * BK + s * 32 + quad * 8;
        a32[buf][rt][s][0] = ((const float4*)p)[0];
        a32[buf][rt][s][1] = ((const float4*)p)[1];
      }
  };
  auto cvtA = [&](int buf) {
#pragma unroll
    for (int rt = 0; rt < 2; ++rt)
#pragma unroll
      for (int s = 0; s < 2; ++s) {
        float4 lo = a32[buf][rt][s][0], hi = a32[buf][rt][s][1];
        short8 r;
        r[0] = (short)f2bf(lo.x); r[1] = (short)f2bf(lo.y);
        r[2] = (short)f2bf(lo.z); r[3] = (short)f2bf(lo.w);
        r[4] = (short)f2bf(hi.x); r[5] = (short)f2bf(hi.y);
        r[6] = (short)f2bf(hi.z); r[7] = (short)f2bf(hi.w);
        aB[buf][rt][s] = r;
      }
  };
  auto stageB = [&](int kch, u16* dst) {
#pragma unroll
    for (int t = 0; t < 4; ++t)
      gl2lds16(pB + (size_t)t * 8 * KDIM + kch * BK, dst + t * 8 * BK);
  };

  // Prologue
  stageB(kb, lBw0);
  loadA(0, 0);
  asm volatile("s_waitcnt vmcnt(0)" ::: "memory");
  cvtA(0);
  __builtin_amdgcn_s_barrier();

#pragma unroll
  for (int kc = 0; kc < 4; ++kc) {
    const int cur = kc & 1, nxt = cur ^ 1;
    if (kc < 3) {
      stageB(kb + kc + 1, nxt ? lBw1 : lBw0);
      loadA(kc + 1, nxt);
    }
#pragma unroll
    for (int s = 0; s < 2; ++s) {
      const int sl = s * 4 + quad;
      __builtin_amdgcn_s_setprio(1);
#pragma unroll
      for (int ct = 0; ct < 8; ++ct) {
        short8 bF = *(const short8*)
            &lB[cur][(ct * 16 + colid) * BK + ((sl ^ csw) * 8)];
        acc[0][ct] = __builtin_amdgcn_mfma_f32_16x16x32_bf16(
            aB[cur][0][s], bF, acc[0][ct], 0, 0, 0);
        acc[1][ct] = __builtin_amdgcn_mfma_f32_16x16x32_bf16(
            aB[cur][1][s], bF, acc[1][ct], 0, 0, 0);
      }
      __builtin_amdgcn_s_setprio(0);
    }
    if (kc < 3) {
      asm volatile("s_waitcnt vmcnt(0)" ::: "memory");
      cvtA(nxt);
      __builtin_amdgcn_s_barrier();
    }
  }

  // Store fp16 rows; b1 folded into U (h = relu(U' + V) later).
  // C/D layout: n = n0 + ct*16 + colid, r = r0 + wid*32 + rt*16 + quad*4 + j.
  float b1v[8];
#pragma unroll
  for (int ct = 0; ct < 8; ++ct)
    b1v[ct] = isV ? 0.f : b1[n0 + ct * 16 + colid];
#pragma unroll
  for (int rt = 0; rt < 2; ++rt)
#pragma unroll
    for (int j = 0; j < 4; ++j) {
      int r = r0 + wid * 32 + rt * 16 + quad * 4 + j;
      if (r < NR) {
#pragma unroll
        for (int ct = 0; ct < 8; ++ct)
          Oh[(size_t)r * HDIM + n0 + ct * 16 + colid] =
              f2h(acc[rt][ct][j] + b1v[ct]);
      }
    }
}

// Edge pass: pure streaming gather. 8 lanes per edge; lane li owns cols
// [li*32, +32) (fp16, 4x16B contiguous loads per table). No LDS, no
// barriers. launch_bounds(256,8): 8 blocks/CU (R11's 4 capped occupancy
// at 47% -- latency-bound gathers want max waves).
__global__ __launch_bounds__(256, 8) void edge_kernel(
    const u16* __restrict__ U, const u16* __restrict__ V,
    const int* __restrict__ row, const int* __restrict__ col,
    const float* __restrict__ w2, const float* __restrict__ b2,
    float* __restrict__ out, int E) {
  const int tid  = threadIdx.x;
  const int lane = tid & 63;
  const int wid  = tid >> 6;
  const int li   = lane & 7;        // lane-in-edge
  const int eg   = lane >> 3;       // edge-in-wave (0..7)

  float w2v[32];
#pragma unroll
  for (int i = 0; i < 32; ++i) w2v[i] = w2[li * 32 + i];
  const float b2v = b2[0];

  for (int base = blockIdx.x * 32; base < E; base += gridDim.x * 32) {
    const int e  = base + wid * 8 + eg;
    const int ee = min(e, E - 1);
    const short8* up = (const short8*)(U + (size_t)row[ee] * HDIM + li * 32);
    const short8* vp = (const short8*)(V + (size_t)col[ee] * HDIM + li * 32);
    short8 ub[4], vb[4];
#pragma unroll
    for (int t = 0; t < 4; ++t) { ub[t] = up[t]; vb[t] = vp[t]; }
    float s = 0.f;
#pragma unroll
    for (int t = 0; t < 4; ++t)
#pragma unroll
      for (int i = 0; i < 8; ++i) {
        float h = h2f((u16)ub[t][i]) + h2f((u16)vb[t][i]);
        s += fmaxf(h, 0.f) * w2v[t * 8 + i];
      }
    s += __shfl_xor(s, 1, 8);
    s += __shfl_xor(s, 2, 8);
    s += __shfl_xor(s, 4, 8);
    if (li == 0 && e < E) out[e] = s + b2v;
  }
}

// Correct-but-slow fp32 fallback (only if ws too small): 16 edges/block.
__global__ void fallback_kernel(
    const float* __restrict__ zd, const float* __restrict__ zt,
    const int* __restrict__ row, const int* __restrict__ col,
    const float* __restrict__ W1, const float* __restrict__ b1,
    const float* __restrict__ W2, const float* __restrict__ b2,
    float* __restrict__ out, int E) {
  __shared__ float zc[16][512];
  __shared__ float red[4][16];
  const int e0 = blockIdx.x * 16;
  const int tid = threadIdx.x;
  for (int i = tid; i < 16 * 512; i += 256) {
    int e = i >> 9, k = i & 511;
    int ge = min(e0 + e, E - 1);
    zc[e][k] = (k < HDIM) ? zd[(size_t)row[ge] * HDIM + k]
                          : zt[(size_t)col[ge] * HDIM + (k - HDIM)];
  }
  __syncthreads();
  float acc[16];
#pragma unroll
  for (int e = 0; e < 16; ++e) acc[e] = 0.f;
  for (int k = 0; k < KDIM; ++k) {
    float w = W1[k * HDIM + tid];
#pragma unroll
    for (int e = 0; e < 16; ++e) acc[e] += zc[e][k] * w;
  }
  float wv = W2[tid], bv = b1[tid];
  const int lane = tid & 63, wid = tid >> 6;
#pragma unroll
  for (int e = 0; e < 16; ++e) {
    float pv = fmaxf(acc[e] + bv, 0.f) * wv;
#pragma unroll
    for (int off = 32; off >= 1; off >>= 1) pv += __shfl_down(pv, off, 64);
    if (lane == 0) red[wid][e] = pv;
  }
  __syncthreads();
  if (tid < 16) {
    int ge = e0 + tid;
    if (ge < E)
      out[ge] = red[0][tid] + red[1][tid] + red[2][tid] + red[3][tid] + b2[0];
  }
}

extern "C" void kernel_launch(void* const* d_in, const int* in_sizes, int n_in,
                              void* d_out, int out_size, void* d_ws, size_t ws_size,
                              hipStream_t stream) {
  const float* zd_f = (const float*)d_in[0];
  const float* zt_f = (const float*)d_in[1];
  const int*   row  = (const int*)d_in[2];
  const int*   col  = (const int*)d_in[3];
  const float* W1   = (const float*)d_in[4];
  const float* b1   = (const float*)d_in[5];
  const float* W2   = (const float*)d_in[6];
  const float* b2   = (const float*)d_in[7];
  float* out = (float*)d_out;

  const int E  = in_sizes[2];            // 500000
  const int ND = in_sizes[0] / HDIM;     // 50000
  const int NT = in_sizes[1] / HDIM;     // 20000

  size_t off_w1t = 0;                                        // 256KB
  size_t off_U   = (size_t)KDIM * HDIM * sizeof(u16);
  size_t off_V   = off_U + (size_t)ND * HDIM * sizeof(u16);  // U: 25.6MB
  size_t need    = off_V + (size_t)NT * HDIM * sizeof(u16);  // ~36.1MB

  if (ws_size >= need) {
    u16* w1t = (u16*)((char*)d_ws + off_w1t);
    u16* Uh  = (u16*)((char*)d_ws + off_U);
    u16* Vh  = (u16*)((char*)d_ws + off_V);
    const int nUb = ((ND + 127) / 128) * 2;    // 782
    const int nVb = ((NT + 127) / 128) * 2;    // 314
    prep_w1t<<<32, 256, 0, stream>>>(W1, w1t);
    uv_gemm<<<nUb + nVb, 256, 0, stream>>>(zd_f, zt_f, w1t, b1, Uh, Vh,
                                           ND, NT, nUb);
    int egrid = (E + 31) / 32;
    if (egrid > 2048) egrid = 2048;
    edge_kernel<<<egrid, 256, 0, stream>>>(Uh, Vh, row, col, W2, b2,
                                           out, E);
  } else {
    fallback_kernel<<<(E + 15) / 16, 256, 0, stream>>>(
        zd_f, zt_f, row, col, W1, b1, W2, b2, out, E);
  }
}